// Round 2
// baseline (1142.328 us; speedup 1.0000x reference)
//
#include <hip/hip_runtime.h>
#include <math.h>

// ---------------- CSR build ----------------

__global__ void k_init(int* __restrict__ counts, int N) {
    int i = blockIdx.x * blockDim.x + threadIdx.x;
    if (i < N) counts[i] = 1;  // one self-loop per node
}

__global__ void k_count(const int* __restrict__ src, const int* __restrict__ dst,
                        int E, int* __restrict__ counts) {
    int e = blockIdx.x * blockDim.x + threadIdx.x;
    if (e < E) {
        int s = src[e], d = dst[e];
        if (s != d) atomicAdd(&counts[d], 1);
    }
}

__global__ __launch_bounds__(1024) void k_scan(const int* __restrict__ counts,
                                               int* __restrict__ rowptr,
                                               int* __restrict__ cursor, int N) {
    __shared__ int sums[1024];
    int t = threadIdx.x;
    int per = (N + 1023) >> 10;
    int start = t * per, end = min(start + per, N);
    int loc = 0;
    for (int i = start; i < end; i++) loc += counts[i];
    sums[t] = loc;
    __syncthreads();
    for (int off = 1; off < 1024; off <<= 1) {
        int v = (t >= off) ? sums[t - off] : 0;
        __syncthreads();
        sums[t] += v;
        __syncthreads();
    }
    int run = (t > 0) ? sums[t - 1] : 0;
    for (int i = start; i < end; i++) {
        rowptr[i] = run; cursor[i] = run; run += counts[i];
    }
    if (start < N && end == N) rowptr[N] = run;
}

__global__ void k_fill(const int* __restrict__ src, const int* __restrict__ dst,
                       int E, int N, int* __restrict__ cursor, int* __restrict__ colA) {
    int i = blockIdx.x * blockDim.x + threadIdx.x;
    if (i < E) {
        int s = src[i], d = dst[i];
        if (s != d) { int p = atomicAdd(&cursor[d], 1); colA[p] = s; }
    } else if (i < E + N) {
        int n = i - E;
        int p = atomicAdd(&cursor[n], 1); colA[p] = n;
    }
}

// ---------------- fp32 GEMM: C[M,128] (+)= A[M,K] @ W[K, 128 cols of ldw] + bias ----------------
// BM=128, BN=128 (fixed), BK=16. 256 threads, 8x8 per thread.

__global__ __launch_bounds__(256) void gemm128(
    const float* __restrict__ A, int M, int K,
    const float* __restrict__ W, int ldw,
    const float* __restrict__ bias,   // may be null
    float* __restrict__ C, int relu, int accum)
{
    __shared__ __align__(16) float At[16 * 132]; // [k][row], padded
    __shared__ __align__(16) float Bs[16 * 132]; // [k][col], padded

    int m0 = blockIdx.x * 128;
    int tid = threadIdx.x;
    int tc = tid & 15;        // 0..15 -> cols tc*8..+8
    int tr = tid >> 4;        // 0..15 -> rows tr*8..+8

    float acc[8][8];
#pragma unroll
    for (int i = 0; i < 8; i++)
#pragma unroll
        for (int j = 0; j < 8; j++) acc[i][j] = 0.f;

    bool fastA = ((K & 15) == 0);

    for (int k0 = 0; k0 < K; k0 += 16) {
        // stage A tile transposed: 128 rows x 16 k
#pragma unroll
        for (int idx = tid; idx < 512; idx += 256) {
            int row = idx >> 2, q = idx & 3;
            int gr = m0 + row, gk = k0 + q * 4;
            float4 v = make_float4(0.f, 0.f, 0.f, 0.f);
            if (gr < M) {
                if (fastA) {
                    v = *(const float4*)(A + (size_t)gr * K + gk);
                } else {
                    float* vv = (float*)&v;
                    for (int i = 0; i < 4; i++)
                        if (gk + i < K) vv[i] = A[(size_t)gr * K + gk + i];
                }
            }
            At[(q * 4 + 0) * 132 + row] = v.x;
            At[(q * 4 + 1) * 132 + row] = v.y;
            At[(q * 4 + 2) * 132 + row] = v.z;
            At[(q * 4 + 3) * 132 + row] = v.w;
        }
        // stage B tile: 16 k x 128 cols
#pragma unroll
        for (int idx = tid; idx < 512; idx += 256) {
            int k = idx >> 5, cq = idx & 31;
            float4 v = make_float4(0.f, 0.f, 0.f, 0.f);
            if (k0 + k < K)
                v = *(const float4*)(W + (size_t)(k0 + k) * ldw + cq * 4);
            *(float4*)&Bs[k * 132 + cq * 4] = v;
        }
        __syncthreads();

#pragma unroll
        for (int kk = 0; kk < 16; kk++) {
            float4 a0 = *(float4*)&At[kk * 132 + tr * 8];
            float4 a1 = *(float4*)&At[kk * 132 + tr * 8 + 4];
            float4 b0 = *(float4*)&Bs[kk * 132 + tc * 8];
            float4 b1 = *(float4*)&Bs[kk * 132 + tc * 8 + 4];
            float a[8] = {a0.x, a0.y, a0.z, a0.w, a1.x, a1.y, a1.z, a1.w};
            float b[8] = {b0.x, b0.y, b0.z, b0.w, b1.x, b1.y, b1.z, b1.w};
#pragma unroll
            for (int i = 0; i < 8; i++)
#pragma unroll
                for (int j = 0; j < 8; j++)
                    acc[i][j] = fmaf(a[i], b[j], acc[i][j]);
        }
        __syncthreads();
    }

    // epilogue
#pragma unroll
    for (int i = 0; i < 8; i++) {
        int gr = m0 + tr * 8 + i;
        if (gr < M) {
            float4 o0, o1;
            float* p0 = (float*)&o0; float* p1 = (float*)&o1;
            float4 c0 = make_float4(0.f,0.f,0.f,0.f), c1 = make_float4(0.f,0.f,0.f,0.f);
            if (accum) {
                c0 = *(const float4*)(C + (size_t)gr * 128 + tc * 8);
                c1 = *(const float4*)(C + (size_t)gr * 128 + tc * 8 + 4);
            }
            const float* pc0 = (const float*)&c0; const float* pc1 = (const float*)&c1;
#pragma unroll
            for (int j = 0; j < 4; j++) {
                float v0 = acc[i][j]     + pc0[j];
                float v1 = acc[i][j + 4] + pc1[j];
                if (bias) { v0 += bias[tc * 8 + j]; v1 += bias[tc * 8 + j + 4]; }
                if (relu) { v0 = fmaxf(v0, 0.f); v1 = fmaxf(v1, 0.f); }
                p0[j] = v0; p1[j] = v1;
            }
            *(float4*)(C + (size_t)gr * 128 + tc * 8)     = o0;
            *(float4*)(C + (size_t)gr * 128 + tc * 8 + 4) = o1;
        }
    }
}

// ---------------- GATv2 edge kernel: one wave per (node, head) ----------------
// xl, xr: [N,128] for this head. Online softmax over in-edges (CSR), fused bias(+relu).

__global__ __launch_bounds__(64) void gat_edge(
    const float* __restrict__ xl, const float* __restrict__ xr,
    const float* __restrict__ att,   // [128]
    const float* __restrict__ bias,  // [128] (pre-offset per head)
    const int* __restrict__ rowptr, const int* __restrict__ colA,
    float* __restrict__ out, int ldo,
    int N, int relu)
{
    int n = blockIdx.x;
    int d = threadIdx.x;  // dims d and d+64

    float xr0 = xr[(size_t)n * 128 + d];
    float xr1 = xr[(size_t)n * 128 + d + 64];
    float at0 = att[d], at1 = att[d + 64];

    int k0 = rowptr[n], k1 = rowptr[n + 1];
    float m = -INFINITY, s = 0.f, o0 = 0.f, o1 = 0.f;

    if (k0 < k1) {
        int srcn = colA[k0];
        const float* vp = xl + (size_t)srcn * 128;
        float v0 = vp[d], v1 = vp[d + 64];
        for (int k = k0; k < k1; k++) {
            float nv0 = 0.f, nv1 = 0.f;
            if (k + 1 < k1) {
                int ns = colA[k + 1];
                const float* np = xl + (size_t)ns * 128;
                nv0 = np[d]; nv1 = np[d + 64];
            }
            float t0 = v0 + xr0; t0 = (t0 > 0.f) ? t0 : 0.2f * t0;
            float t1 = v1 + xr1; t1 = (t1 > 0.f) ? t1 : 0.2f * t1;
            float c = t0 * at0 + t1 * at1;
#pragma unroll
            for (int off = 32; off > 0; off >>= 1)
                c += __shfl_xor(c, off);
            if (c > m) {
                float sc = __expf(m - c);
                s *= sc; o0 *= sc; o1 *= sc;
                m = c;
            }
            float p = __expf(c - m);
            s += p; o0 += p * v0; o1 += p * v1;
            v0 = nv0; v1 = nv1;
        }
    }

    float inv = 1.f / (s + 1e-16f);
    float r0 = o0 * inv + bias[d];
    float r1 = o1 * inv + bias[d + 64];
    if (relu) { r0 = fmaxf(r0, 0.f); r1 = fmaxf(r1, 0.f); }
    out[(size_t)n * ldo + d] = r0;
    out[(size_t)n * ldo + d + 64] = r1;
}

// ---------------- launch ----------------

extern "C" void kernel_launch(void* const* d_in, const int* in_sizes, int n_in,
                              void* d_out, int out_size, void* d_ws, size_t ws_size,
                              hipStream_t stream) {
    const float* x    = (const float*)d_in[0];
    const int* ei     = (const int*)d_in[1];      // harness converts int64 -> int32
    const float* W1   = (const float*)d_in[2];
    const float* b1   = (const float*)d_in[3];
    const float* W2   = (const float*)d_in[4];
    const float* b2   = (const float*)d_in[5];
    const float* Wl1  = (const float*)d_in[6];
    const float* bl1  = (const float*)d_in[7];
    const float* Wr1  = (const float*)d_in[8];
    const float* br1  = (const float*)d_in[9];
    const float* att1 = (const float*)d_in[10];
    const float* bias1= (const float*)d_in[11];
    const float* Wl2  = (const float*)d_in[12];
    const float* bl2  = (const float*)d_in[13];
    const float* Wr2  = (const float*)d_in[14];
    const float* br2  = (const float*)d_in[15];
    const float* att2 = (const float*)d_in[16];
    const float* bias2= (const float*)d_in[17];

    int E = in_sizes[1] / 2;
    int N = in_sizes[0] / 5;
    const int* srcE = ei;
    const int* dstE = ei + E;

    float* dout = (float*)d_out;  // holds h0 [N,128], then final output

    // workspace layout (~130 MB)
    float* bufA = (float*)d_ws;                   // N*128 (xl_h)
    float* bufB = bufA + (size_t)N * 128;         // N*128 (xr_h)
    float* bufC = bufB + (size_t)N * 128;         // N*128 (head out / MLP hidden)
    float* accL = bufC + (size_t)N * 128;         // N*128 (xl2 accumulator)
    float* accR = accL + (size_t)N * 128;         // N*128 (xr2 accumulator)
    int* rowptr = (int*)(accR + (size_t)N * 128); // N+1
    int* cursor = rowptr + (N + 1);               // N
    int* counts = cursor + N;                     // N
    int* colA   = counts + N;                     // E+N

    // ---- CSR build ----
    k_init <<<(N + 255) / 256, 256, 0, stream>>>(counts, N);
    k_count<<<(E + 255) / 256, 256, 0, stream>>>(srcE, dstE, E, counts);
    k_scan <<<1, 1024, 0, stream>>>(counts, rowptr, cursor, N);
    k_fill <<<(E + N + 255) / 256, 256, 0, stream>>>(srcE, dstE, E, N, cursor, colA);

    int mb = (N + 127) / 128;

    // ---- MLP: h0 = relu(x@W1+b1)@W2+b2 -> dout ----
    gemm128<<<mb, 256, 0, stream>>>(x, N, 5, W1, 128, b1, bufC, 1, 0);
    gemm128<<<mb, 256, 0, stream>>>(bufC, N, 128, W2, 128, b2, dout, 0, 0);

    // ---- GAT1 (4 heads); accumulate xl2/xr2 = h1 @ Wl2/Wr2 head-by-head ----
    for (int h = 0; h < 4; h++) {
        gemm128<<<mb, 256, 0, stream>>>(dout, N, 128, Wl1 + h * 128, 512, bl1 + h * 128, bufA, 0, 0);
        gemm128<<<mb, 256, 0, stream>>>(dout, N, 128, Wr1 + h * 128, 512, br1 + h * 128, bufB, 0, 0);
        gat_edge<<<N, 64, 0, stream>>>(bufA, bufB, att1 + h * 128, bias1 + h * 128,
                                       rowptr, colA, bufC, 128, N, 1);
        // accL/accR (+)= bufC @ Wl2[h*128:(h+1)*128, :], bias added on first head
        gemm128<<<mb, 256, 0, stream>>>(bufC, N, 128, Wl2 + (size_t)h * 128 * 128, 128,
                                        (h == 0) ? bl2 : nullptr, accL, 0, h > 0);
        gemm128<<<mb, 256, 0, stream>>>(bufC, N, 128, Wr2 + (size_t)h * 128 * 128, 128,
                                        (h == 0) ? br2 : nullptr, accR, 0, h > 0);
    }

    // ---- GAT2 (1 head) -> dout ----
    gat_edge<<<N, 64, 0, stream>>>(accL, accR, att2, bias2, rowptr, colA, dout, 128, N, 0);
}

// Round 3
// 738.119 us; speedup vs baseline: 1.5476x; 1.5476x over previous
//
#include <hip/hip_runtime.h>
#include <math.h>

typedef __attribute__((ext_vector_type(8))) short bf16x8;
typedef __attribute__((ext_vector_type(4))) float f32x4;
typedef unsigned short ushort;

static __device__ __forceinline__ ushort f2bf(float f) {
    unsigned u = __float_as_uint(f);
    u = u + 0x7fff + ((u >> 16) & 1);
    return (ushort)(u >> 16);
}
static __device__ __forceinline__ float bf2f(ushort h) {
    return __uint_as_float(((unsigned)h) << 16);
}

// ---------------- CSR build ----------------

__global__ void k_init(int* __restrict__ counts, int N) {
    int i = blockIdx.x * blockDim.x + threadIdx.x;
    if (i < N) counts[i] = 1;  // self-loop
}

__global__ void k_count(const int* __restrict__ src, const int* __restrict__ dst,
                        int E, int* __restrict__ counts) {
    int e = blockIdx.x * blockDim.x + threadIdx.x;
    if (e < E) {
        int s = src[e], d = dst[e];
        if (s != d) atomicAdd(&counts[d], 1);
    }
}

__global__ __launch_bounds__(256) void k_blocksum(const int* __restrict__ counts, int N,
                                                  int* __restrict__ bsum) {
    __shared__ int s[256];
    int t = threadIdx.x, i = blockIdx.x * 256 + t;
    s[t] = (i < N) ? counts[i] : 0;
    __syncthreads();
    for (int off = 128; off > 0; off >>= 1) {
        if (t < off) s[t] += s[t + off];
        __syncthreads();
    }
    if (t == 0) bsum[blockIdx.x] = s[0];
}

__global__ __launch_bounds__(256) void k_scanblocks(const int* __restrict__ bsum, int NB,
                                                    int* __restrict__ boff,
                                                    int* __restrict__ rowptr, int N) {
    __shared__ int s[256];
    int t = threadIdx.x;
    int v = (t < NB) ? bsum[t] : 0;
    s[t] = v;
    __syncthreads();
    for (int off = 1; off < 256; off <<= 1) {
        int u = (t >= off) ? s[t - off] : 0;
        __syncthreads();
        s[t] += u;
        __syncthreads();
    }
    if (t < NB) boff[t] = s[t] - v;
    if (t == NB - 1) rowptr[N] = s[t];
}

__global__ __launch_bounds__(256) void k_scatter(const int* __restrict__ counts, int N,
                                                 const int* __restrict__ boff,
                                                 int* __restrict__ rowptr,
                                                 int* __restrict__ cursor) {
    __shared__ int s[256];
    int t = threadIdx.x, i = blockIdx.x * 256 + t;
    int c = (i < N) ? counts[i] : 0;
    s[t] = c;
    __syncthreads();
    for (int off = 1; off < 256; off <<= 1) {
        int u = (t >= off) ? s[t - off] : 0;
        __syncthreads();
        s[t] += u;
        __syncthreads();
    }
    if (i < N) {
        int excl = boff[blockIdx.x] + s[t] - c;
        rowptr[i] = excl;
        cursor[i] = excl;
    }
}

__global__ void k_fill(const int* __restrict__ src, const int* __restrict__ dst,
                       int E, int N, int* __restrict__ cursor, int* __restrict__ colA) {
    int i = blockIdx.x * blockDim.x + threadIdx.x;
    if (i < E) {
        int s = src[i], d = dst[i];
        if (s != d) { int p = atomicAdd(&cursor[d], 1); colA[p] = s; }
    } else if (i < E + N) {
        int n = i - E;
        int p = atomicAdd(&cursor[n], 1); colA[p] = n;
    }
}

// ---------------- weight repack into MFMA-fragment-major, split bf16 ----------------
// Per job: W fp32 [K=128, ldw], rows rowoff.., cols col0..col0+127.
// Wf[ks][n][l][j] = W[rowoff + ks*32 + (l>>4)*8 + j][col0 + n*16 + (l&15)]
// slot stride 16384 ushorts.

__global__ __launch_bounds__(256) void k_repack(
    const float* __restrict__ W2, const float* __restrict__ Wl1,
    const float* __restrict__ Wr1, const float* __restrict__ Wl2,
    const float* __restrict__ Wr2,
    ushort* __restrict__ wfh, ushort* __restrict__ wfl)
{
    int job = blockIdx.y;
    int t = blockIdx.x * 256 + threadIdx.x;  // 0..2047
    int ks = t >> 9, n = (t >> 6) & 7, l = t & 63;

    const float* W; int ldw, rowoff, col0;
    if (job == 0)      { W = W2;  ldw = 128; rowoff = 0;              col0 = 0; }
    else if (job < 5)  { W = Wl1; ldw = 512; rowoff = 0;              col0 = (job - 1) * 128; }
    else if (job < 9)  { W = Wr1; ldw = 512; rowoff = 0;              col0 = (job - 5) * 128; }
    else if (job < 13) { W = Wl2; ldw = 128; rowoff = (job - 9) * 128;  col0 = 0; }
    else               { W = Wr2; ldw = 128; rowoff = (job - 13) * 128; col0 = 0; }

    int krow = rowoff + ks * 32 + (l >> 4) * 8;
    int col = col0 + n * 16 + (l & 15);
    size_t dbase = (size_t)job * 16384 + (((size_t)(ks * 8 + n)) * 64 + l) * 8;
#pragma unroll
    for (int j = 0; j < 8; j++) {
        float v = W[(size_t)(krow + j) * ldw + col];
        ushort h = f2bf(v);
        ushort lo = f2bf(v - bf2f(h));
        wfh[dbase + j] = h;
        wfl[dbase + j] = lo;
    }
}

// ---------------- MLP layer 1: relu(x[N,5] @ W1[5,128] + b1) -> split bf16 ----------------

__global__ __launch_bounds__(256) void k_mlp1(
    const float* __restrict__ x, const float* __restrict__ W1, const float* __restrict__ b1,
    ushort* __restrict__ outh, ushort* __restrict__ outl, int N)
{
    int n = blockIdx.x * 2 + (threadIdx.x >> 7);
    int j = threadIdx.x & 127;
    if (n >= N) return;
    float s = b1[j];
#pragma unroll
    for (int k = 0; k < 5; k++) s = fmaf(x[(size_t)n * 5 + k], W1[k * 128 + j], s);
    s = fmaxf(s, 0.f);
    ushort h = f2bf(s);
    outh[(size_t)n * 128 + j] = h;
    outl[(size_t)n * 128 + j] = f2bf(s - bf2f(h));
}

// ---------------- MFMA GEMM (bf16x3): C[M,128] (+)= (Ah+Al)[M,128] @ Wslot ----------------
// 256 threads = 4 waves; block tile 128 rows; wave tile 32 rows x 128 cols.

__global__ __launch_bounds__(256) void gemm_mfma(
    const ushort* __restrict__ Ah, const ushort* __restrict__ Al,
    const ushort* __restrict__ wfh, const ushort* __restrict__ wfl,  // pre-offset to slot
    const float* __restrict__ bias,   // may be null
    float* __restrict__ C,            // fp32 out (may be null)
    ushort* __restrict__ Ch, ushort* __restrict__ Cl,  // split out (may be null)
    int M, int relu, int accum)
{
    int tid = threadIdx.x;
    int w = tid >> 6, l = tid & 63;
    int m0 = blockIdx.x * 128 + w * 32;
    int lr = l & 15, kg = l >> 4;

    f32x4 acc[2][8];
#pragma unroll
    for (int i = 0; i < 2; i++)
#pragma unroll
        for (int j = 0; j < 8; j++) acc[i][j] = (f32x4){0.f, 0.f, 0.f, 0.f};

    int row0 = m0 + lr, row1 = m0 + 16 + lr;
    bool ok0 = row0 < M, ok1 = row1 < M;
    const bf16x8 zz = {0, 0, 0, 0, 0, 0, 0, 0};

#pragma unroll
    for (int ks = 0; ks < 4; ks++) {
        int koff = ks * 32 + kg * 8;
        bf16x8 a0h = ok0 ? *(const bf16x8*)(Ah + (size_t)row0 * 128 + koff) : zz;
        bf16x8 a0l = ok0 ? *(const bf16x8*)(Al + (size_t)row0 * 128 + koff) : zz;
        bf16x8 a1h = ok1 ? *(const bf16x8*)(Ah + (size_t)row1 * 128 + koff) : zz;
        bf16x8 a1l = ok1 ? *(const bf16x8*)(Al + (size_t)row1 * 128 + koff) : zz;
#pragma unroll
        for (int n = 0; n < 8; n++) {
            size_t bo = (((size_t)(ks * 8 + n)) * 64 + l) * 8;
            bf16x8 bh = *(const bf16x8*)(wfh + bo);
            bf16x8 bl = *(const bf16x8*)(wfl + bo);
            acc[0][n] = __builtin_amdgcn_mfma_f32_16x16x32_bf16(a0h, bh, acc[0][n], 0, 0, 0);
            acc[0][n] = __builtin_amdgcn_mfma_f32_16x16x32_bf16(a0h, bl, acc[0][n], 0, 0, 0);
            acc[0][n] = __builtin_amdgcn_mfma_f32_16x16x32_bf16(a0l, bh, acc[0][n], 0, 0, 0);
            acc[1][n] = __builtin_amdgcn_mfma_f32_16x16x32_bf16(a1h, bh, acc[1][n], 0, 0, 0);
            acc[1][n] = __builtin_amdgcn_mfma_f32_16x16x32_bf16(a1h, bl, acc[1][n], 0, 0, 0);
            acc[1][n] = __builtin_amdgcn_mfma_f32_16x16x32_bf16(a1l, bh, acc[1][n], 0, 0, 0);
        }
    }

    float bcol[8];
#pragma unroll
    for (int n = 0; n < 8; n++) bcol[n] = bias ? bias[n * 16 + lr] : 0.f;

#pragma unroll
    for (int mf = 0; mf < 2; mf++) {
#pragma unroll
        for (int r = 0; r < 4; r++) {
            int row = m0 + mf * 16 + kg * 4 + r;
            if (row >= M) continue;
#pragma unroll
            for (int n = 0; n < 8; n++) {
                size_t idx = (size_t)row * 128 + n * 16 + lr;
                float v = acc[mf][n][r] + bcol[n];
                if (accum) v += C[idx];
                if (relu) v = fmaxf(v, 0.f);
                if (C) C[idx] = v;
                if (Ch) {
                    ushort h = f2bf(v);
                    Ch[idx] = h;
                    Cl[idx] = f2bf(v - bf2f(h));
                }
            }
        }
    }
}

// ---------------- GATv2 edge kernel: one wave per node ----------------

__global__ __launch_bounds__(64) void gat_edge(
    const float* __restrict__ xl, const float* __restrict__ xr,
    const float* __restrict__ att, const float* __restrict__ bias,
    const int* __restrict__ rowptr, const int* __restrict__ colA,
    float* __restrict__ outF,             // fp32 out (may be null)
    ushort* __restrict__ outH, ushort* __restrict__ outL,  // split out (may be null)
    int N, int relu)
{
    int n = blockIdx.x;
    int d = threadIdx.x;

    float xr0 = xr[(size_t)n * 128 + d];
    float xr1 = xr[(size_t)n * 128 + d + 64];
    float at0 = att[d], at1 = att[d + 64];

    int k0 = rowptr[n], k1 = rowptr[n + 1];
    float m = -INFINITY, s = 0.f, o0 = 0.f, o1 = 0.f;

    if (k0 < k1) {
        int srcn = colA[k0];
        const float* vp = xl + (size_t)srcn * 128;
        float v0 = vp[d], v1 = vp[d + 64];
        for (int k = k0; k < k1; k++) {
            float nv0 = 0.f, nv1 = 0.f;
            if (k + 1 < k1) {
                int ns = colA[k + 1];
                const float* np = xl + (size_t)ns * 128;
                nv0 = np[d]; nv1 = np[d + 64];
            }
            float t0 = v0 + xr0; t0 = (t0 > 0.f) ? t0 : 0.2f * t0;
            float t1 = v1 + xr1; t1 = (t1 > 0.f) ? t1 : 0.2f * t1;
            float c = t0 * at0 + t1 * at1;
#pragma unroll
            for (int off = 32; off > 0; off >>= 1)
                c += __shfl_xor(c, off);
            if (c > m) {
                float sc = __expf(m - c);
                s *= sc; o0 *= sc; o1 *= sc;
                m = c;
            }
            float p = __expf(c - m);
            s += p; o0 += p * v0; o1 += p * v1;
            v0 = nv0; v1 = nv1;
        }
    }

    float inv = 1.f / (s + 1e-16f);
    float r0 = o0 * inv + bias[d];
    float r1 = o1 * inv + bias[d + 64];
    if (relu) { r0 = fmaxf(r0, 0.f); r1 = fmaxf(r1, 0.f); }
    size_t i0 = (size_t)n * 128 + d, i1 = i0 + 64;
    if (outF) { outF[i0] = r0; outF[i1] = r1; }
    if (outH) {
        ushort h0 = f2bf(r0), h1 = f2bf(r1);
        outH[i0] = h0; outL[i0] = f2bf(r0 - bf2f(h0));
        outH[i1] = h1; outL[i1] = f2bf(r1 - bf2f(h1));
    }
}

// ---------------- launch ----------------

extern "C" void kernel_launch(void* const* d_in, const int* in_sizes, int n_in,
                              void* d_out, int out_size, void* d_ws, size_t ws_size,
                              hipStream_t stream) {
    const float* x    = (const float*)d_in[0];
    const int* ei     = (const int*)d_in[1];
    const float* W1   = (const float*)d_in[2];
    const float* b1   = (const float*)d_in[3];
    const float* W2   = (const float*)d_in[4];
    const float* b2   = (const float*)d_in[5];
    const float* Wl1  = (const float*)d_in[6];
    const float* bl1  = (const float*)d_in[7];
    const float* Wr1  = (const float*)d_in[8];
    const float* br1  = (const float*)d_in[9];
    const float* att1 = (const float*)d_in[10];
    const float* bias1= (const float*)d_in[11];
    const float* Wl2  = (const float*)d_in[12];
    const float* bl2  = (const float*)d_in[13];
    const float* Wr2  = (const float*)d_in[14];
    const float* br2  = (const float*)d_in[15];
    const float* att2 = (const float*)d_in[16];
    const float* bias2= (const float*)d_in[17];

    int E = in_sizes[1] / 2;
    int N = in_sizes[0] / 5;
    const int* srcE = ei;
    const int* dstE = ei + E;

    float* dout = (float*)d_out;   // doubles as xl buffer during head loop
    size_t NF = (size_t)N * 128;

    // workspace layout (~133 MB)
    float* bufB = (float*)d_ws;            // xr
    float* accL = bufB + NF;
    float* accR = accL + NF;
    ushort* h0h = (ushort*)(accR + NF);
    ushort* h0l = h0h + NF;
    ushort* cCh = h0l + NF;
    ushort* cCl = cCh + NF;
    ushort* wfh = cCl + NF;                // 17*16384
    ushort* wfl = wfh + 17 * 16384;
    int* rowptr = (int*)(wfl + 17 * 16384);
    int* cursor = rowptr + (N + 1);
    int* counts = cursor + N;
    int* colA   = counts + N;              // E+N
    int* bsum   = colA + (E + N);          // NB
    int* boff   = bsum + 256;

    int NB = (N + 255) / 256;

    // ---- CSR ----
    k_init <<<(N + 255) / 256, 256, 0, stream>>>(counts, N);
    k_count<<<(E + 255) / 256, 256, 0, stream>>>(srcE, dstE, E, counts);
    k_blocksum <<<NB, 256, 0, stream>>>(counts, N, bsum);
    k_scanblocks<<<1, 256, 0, stream>>>(bsum, NB, boff, rowptr, N);
    k_scatter  <<<NB, 256, 0, stream>>>(counts, N, boff, rowptr, cursor);
    k_fill <<<(E + N + 255) / 256, 256, 0, stream>>>(srcE, dstE, E, N, cursor, colA);

    // ---- weight repack (17 jobs) ----
    {
        dim3 g(8, 17);
        k_repack<<<g, 256, 0, stream>>>(W2, Wl1, Wr1, Wl2, Wr2, wfh, wfl);
    }

    int mb = (N + 127) / 128;

    // ---- MLP ----
    k_mlp1<<<(N + 1) / 2, 256, 0, stream>>>(x, W1, b1, cCh, cCl, N);
    // h0 = cC @ W2 + b2 (split output only)
    gemm_mfma<<<mb, 256, 0, stream>>>(cCh, cCl, wfh, wfl, b2,
                                      nullptr, h0h, h0l, N, 0, 0);

    // ---- GAT1 heads ----
    for (int h = 0; h < 4; h++) {
        gemm_mfma<<<mb, 256, 0, stream>>>(h0h, h0l, wfh + (1 + h) * 16384, wfl + (1 + h) * 16384,
                                          bl1 + h * 128, dout, nullptr, nullptr, N, 0, 0);
        gemm_mfma<<<mb, 256, 0, stream>>>(h0h, h0l, wfh + (5 + h) * 16384, wfl + (5 + h) * 16384,
                                          br1 + h * 128, bufB, nullptr, nullptr, N, 0, 0);
        gat_edge<<<N, 64, 0, stream>>>(dout, bufB, att1 + h * 128, bias1 + h * 128,
                                       rowptr, colA, nullptr, cCh, cCl, N, 1);
        gemm_mfma<<<mb, 256, 0, stream>>>(cCh, cCl, wfh + (9 + h) * 16384, wfl + (9 + h) * 16384,
                                          (h == 0) ? bl2 : nullptr, accL, nullptr, nullptr, N, 0, h > 0);
        gemm_mfma<<<mb, 256, 0, stream>>>(cCh, cCl, wfh + (13 + h) * 16384, wfl + (13 + h) * 16384,
                                          (h == 0) ? br2 : nullptr, accR, nullptr, nullptr, N, 0, h > 0);
    }

    // ---- GAT2 ----
    gat_edge<<<N, 64, 0, stream>>>(accL, accR, att2, bias2, rowptr, colA,
                                   dout, nullptr, nullptr, N, 0);
}

// Round 4
// 456.002 us; speedup vs baseline: 2.5051x; 1.6187x over previous
//
#include <hip/hip_runtime.h>
#include <math.h>

typedef __attribute__((ext_vector_type(8))) short bf16x8;
typedef __attribute__((ext_vector_type(4))) float f32x4;
typedef unsigned short ushort;

static __device__ __forceinline__ ushort f2bf(float f) {
    unsigned u = __float_as_uint(f);
    u = u + 0x7fff + ((u >> 16) & 1);
    return (ushort)(u >> 16);
}
static __device__ __forceinline__ float bf2f(ushort h) {
    return __uint_as_float(((unsigned)h) << 16);
}

// ---------------- CSR build ----------------

__global__ void k_init(int* __restrict__ counts, int N) {
    int i = blockIdx.x * blockDim.x + threadIdx.x;
    if (i < N) counts[i] = 1;  // self-loop
}

__global__ void k_count(const int* __restrict__ src, const int* __restrict__ dst,
                        int E, int* __restrict__ counts) {
    int e = blockIdx.x * blockDim.x + threadIdx.x;
    if (e < E) {
        int s = src[e], d = dst[e];
        if (s != d) atomicAdd(&counts[d], 1);
    }
}

__global__ __launch_bounds__(256) void k_blocksum(const int* __restrict__ counts, int N,
                                                  int* __restrict__ bsum) {
    __shared__ int s[256];
    int t = threadIdx.x, i = blockIdx.x * 256 + t;
    s[t] = (i < N) ? counts[i] : 0;
    __syncthreads();
    for (int off = 128; off > 0; off >>= 1) {
        if (t < off) s[t] += s[t + off];
        __syncthreads();
    }
    if (t == 0) bsum[blockIdx.x] = s[0];
}

__global__ __launch_bounds__(256) void k_scanblocks(const int* __restrict__ bsum, int NB,
                                                    int* __restrict__ boff,
                                                    int* __restrict__ rowptr, int N) {
    __shared__ int s[256];
    int t = threadIdx.x;
    int v = (t < NB) ? bsum[t] : 0;
    s[t] = v;
    __syncthreads();
    for (int off = 1; off < 256; off <<= 1) {
        int u = (t >= off) ? s[t - off] : 0;
        __syncthreads();
        s[t] += u;
        __syncthreads();
    }
    if (t < NB) boff[t] = s[t] - v;
    if (t == NB - 1) rowptr[N] = s[t];
}

__global__ __launch_bounds__(256) void k_scatter(const int* __restrict__ counts, int N,
                                                 const int* __restrict__ boff,
                                                 int* __restrict__ rowptr,
                                                 int* __restrict__ cursor) {
    __shared__ int s[256];
    int t = threadIdx.x, i = blockIdx.x * 256 + t;
    int c = (i < N) ? counts[i] : 0;
    s[t] = c;
    __syncthreads();
    for (int off = 1; off < 256; off <<= 1) {
        int u = (t >= off) ? s[t - off] : 0;
        __syncthreads();
        s[t] += u;
        __syncthreads();
    }
    if (i < N) {
        int excl = boff[blockIdx.x] + s[t] - c;
        rowptr[i] = excl;
        cursor[i] = excl;
    }
}

__global__ void k_fill(const int* __restrict__ src, const int* __restrict__ dst,
                       int E, int N, int* __restrict__ cursor, int* __restrict__ colA) {
    int i = blockIdx.x * blockDim.x + threadIdx.x;
    if (i < E) {
        int s = src[i], d = dst[i];
        if (s != d) { int p = atomicAdd(&cursor[d], 1); colA[p] = s; }
    } else if (i < E + N) {
        int n = i - E;
        int p = atomicAdd(&cursor[n], 1); colA[p] = n;
    }
}

// ---------------- weight repack into MFMA-fragment-major, split bf16 ----------------
// slot j: 0 = W2; 1-4 = Wl1 head cols; 5-8 = Wr1 head cols; 9-12 = Wl2 k-chunks; 13-16 = Wr2.
// Wf[ks][n][l][j] = W[rowoff + ks*32 + (l>>4)*8 + j][col0 + n*16 + (l&15)], slot stride 16384.

__global__ __launch_bounds__(256) void k_repack(
    const float* __restrict__ W2, const float* __restrict__ Wl1,
    const float* __restrict__ Wr1, const float* __restrict__ Wl2,
    const float* __restrict__ Wr2,
    ushort* __restrict__ wfh, ushort* __restrict__ wfl)
{
    int job = blockIdx.y;
    int t = blockIdx.x * 256 + threadIdx.x;  // 0..2047
    int ks = t >> 9, n = (t >> 6) & 7, l = t & 63;

    const float* W; int ldw, rowoff, col0;
    if (job == 0)      { W = W2;  ldw = 128; rowoff = 0;              col0 = 0; }
    else if (job < 5)  { W = Wl1; ldw = 512; rowoff = 0;              col0 = (job - 1) * 128; }
    else if (job < 9)  { W = Wr1; ldw = 512; rowoff = 0;              col0 = (job - 5) * 128; }
    else if (job < 13) { W = Wl2; ldw = 128; rowoff = (job - 9) * 128;  col0 = 0; }
    else               { W = Wr2; ldw = 128; rowoff = (job - 13) * 128; col0 = 0; }

    int krow = rowoff + ks * 32 + (l >> 4) * 8;
    int col = col0 + n * 16 + (l & 15);
    size_t dbase = (size_t)job * 16384 + (((size_t)(ks * 8 + n)) * 64 + l) * 8;
#pragma unroll
    for (int j = 0; j < 8; j++) {
        float v = W[(size_t)(krow + j) * ldw + col];
        ushort h = f2bf(v);
        ushort lo = f2bf(v - bf2f(h));
        wfh[dbase + j] = h;
        wfl[dbase + j] = lo;
    }
}

// ---------------- MLP layer 1 ----------------

__global__ __launch_bounds__(256) void k_mlp1(
    const float* __restrict__ x, const float* __restrict__ W1, const float* __restrict__ b1,
    ushort* __restrict__ outh, ushort* __restrict__ outl, int N)
{
    int n = blockIdx.x * 2 + (threadIdx.x >> 7);
    int j = threadIdx.x & 127;
    if (n >= N) return;
    float s = b1[j];
#pragma unroll
    for (int k = 0; k < 5; k++) s = fmaf(x[(size_t)n * 5 + k], W1[k * 128 + j], s);
    s = fmaxf(s, 0.f);
    ushort h = f2bf(s);
    outh[(size_t)n * 128 + j] = h;
    outl[(size_t)n * 128 + j] = f2bf(s - bf2f(h));
}

// ---------------- h0 GEMM (bf16x3, B from global): split in, split out ----------------

__global__ __launch_bounds__(256) void gemm_mfma(
    const ushort* __restrict__ Ah, const ushort* __restrict__ Al,
    const ushort* __restrict__ wfh, const ushort* __restrict__ wfl,
    const float* __restrict__ bias,
    ushort* __restrict__ Ch, ushort* __restrict__ Cl,
    int M)
{
    int tid = threadIdx.x;
    int w = tid >> 6, l = tid & 63;
    int m0 = blockIdx.x * 128 + w * 32;
    int lr = l & 15, kg = l >> 4;

    f32x4 acc[2][8];
#pragma unroll
    for (int i = 0; i < 2; i++)
#pragma unroll
        for (int j = 0; j < 8; j++) acc[i][j] = (f32x4){0.f, 0.f, 0.f, 0.f};

    int row0 = m0 + lr, row1 = m0 + 16 + lr;
    bool ok0 = row0 < M, ok1 = row1 < M;
    const bf16x8 zz = {0, 0, 0, 0, 0, 0, 0, 0};

#pragma unroll
    for (int ks = 0; ks < 4; ks++) {
        int koff = ks * 32 + kg * 8;
        bf16x8 a0h = ok0 ? *(const bf16x8*)(Ah + (size_t)row0 * 128 + koff) : zz;
        bf16x8 a0l = ok0 ? *(const bf16x8*)(Al + (size_t)row0 * 128 + koff) : zz;
        bf16x8 a1h = ok1 ? *(const bf16x8*)(Ah + (size_t)row1 * 128 + koff) : zz;
        bf16x8 a1l = ok1 ? *(const bf16x8*)(Al + (size_t)row1 * 128 + koff) : zz;
#pragma unroll
        for (int n = 0; n < 8; n++) {
            size_t bo = (((size_t)(ks * 8 + n)) * 64 + l) * 8;
            bf16x8 bh = *(const bf16x8*)(wfh + bo);
            bf16x8 bl = *(const bf16x8*)(wfl + bo);
            acc[0][n] = __builtin_amdgcn_mfma_f32_16x16x32_bf16(a0h, bh, acc[0][n], 0, 0, 0);
            acc[0][n] = __builtin_amdgcn_mfma_f32_16x16x32_bf16(a0h, bl, acc[0][n], 0, 0, 0);
            acc[0][n] = __builtin_amdgcn_mfma_f32_16x16x32_bf16(a0l, bh, acc[0][n], 0, 0, 0);
            acc[1][n] = __builtin_amdgcn_mfma_f32_16x16x32_bf16(a1h, bh, acc[1][n], 0, 0, 0);
            acc[1][n] = __builtin_amdgcn_mfma_f32_16x16x32_bf16(a1h, bl, acc[1][n], 0, 0, 0);
            acc[1][n] = __builtin_amdgcn_mfma_f32_16x16x32_bf16(a1l, bh, acc[1][n], 0, 0, 0);
        }
    }

#pragma unroll
    for (int mf = 0; mf < 2; mf++) {
#pragma unroll
        for (int r = 0; r < 4; r++) {
            int row = m0 + mf * 16 + kg * 4 + r;
            if (row >= M) continue;
#pragma unroll
            for (int n = 0; n < 8; n++) {
                size_t idx = (size_t)row * 128 + n * 16 + lr;
                float v = acc[mf][n][r] + bias[n * 16 + lr];
                ushort h = f2bf(v);
                Ch[idx] = h;
                Cl[idx] = f2bf(v - bf2f(h));
            }
        }
    }
}

// ---------------- xl/xr projection for all 8 head-slots, LDS-staged B ----------------
// out: [N][8][128] bf16.  slots base = wfh + 1*16384 (Wl1 heads 0-3, Wr1 heads 0-3).

__global__ __launch_bounds__(256) void gemm_xlr1(
    const ushort* __restrict__ Ah, const ushort* __restrict__ Al,  // h0 split [N][128]
    const ushort* __restrict__ wh, const ushort* __restrict__ wl,  // slot-1 base
    const float* __restrict__ bl1, const float* __restrict__ br1,  // [512] each
    ushort* __restrict__ out, int M)
{
    __shared__ __align__(16) ushort Bh[16384];
    __shared__ __align__(16) ushort Bl[16384];

    int tid = threadIdx.x;
    int w = tid >> 6, l = tid & 63;
    int m0 = blockIdx.x * 128 + w * 32;
    int lr = l & 15, kg = l >> 4;

    int row0 = m0 + lr, row1 = m0 + 16 + lr;
    bool ok0 = row0 < M, ok1 = row1 < M;
    const bf16x8 zz = {0, 0, 0, 0, 0, 0, 0, 0};

    bf16x8 a0h[4], a0l[4], a1h[4], a1l[4];
#pragma unroll
    for (int ks = 0; ks < 4; ks++) {
        int koff = ks * 32 + kg * 8;
        a0h[ks] = ok0 ? *(const bf16x8*)(Ah + (size_t)row0 * 128 + koff) : zz;
        a0l[ks] = ok0 ? *(const bf16x8*)(Al + (size_t)row0 * 128 + koff) : zz;
        a1h[ks] = ok1 ? *(const bf16x8*)(Ah + (size_t)row1 * 128 + koff) : zz;
        a1l[ks] = ok1 ? *(const bf16x8*)(Al + (size_t)row1 * 128 + koff) : zz;
    }

    for (int t = 0; t < 8; t++) {
        __syncthreads();
        // stage slot t (32 KB hi + 32 KB lo)
        {
            const float4* gh = (const float4*)(wh + (size_t)t * 16384);
            const float4* gl = (const float4*)(wl + (size_t)t * 16384);
            float4* sh = (float4*)Bh;
            float4* sl = (float4*)Bl;
#pragma unroll
            for (int i = 0; i < 8; i++) {
                sh[i * 256 + tid] = gh[i * 256 + tid];
                sl[i * 256 + tid] = gl[i * 256 + tid];
            }
        }
        __syncthreads();

        f32x4 acc[2][8];
#pragma unroll
        for (int i = 0; i < 2; i++)
#pragma unroll
            for (int j = 0; j < 8; j++) acc[i][j] = (f32x4){0.f, 0.f, 0.f, 0.f};

#pragma unroll
        for (int ks = 0; ks < 4; ks++) {
#pragma unroll
            for (int n = 0; n < 8; n++) {
                int bo = ((ks * 8 + n) * 64 + l) * 8;
                bf16x8 bh = *(const bf16x8*)(Bh + bo);
                bf16x8 bl = *(const bf16x8*)(Bl + bo);
                acc[0][n] = __builtin_amdgcn_mfma_f32_16x16x32_bf16(a0h[ks], bh, acc[0][n], 0, 0, 0);
                acc[0][n] = __builtin_amdgcn_mfma_f32_16x16x32_bf16(a0h[ks], bl, acc[0][n], 0, 0, 0);
                acc[0][n] = __builtin_amdgcn_mfma_f32_16x16x32_bf16(a0l[ks], bh, acc[0][n], 0, 0, 0);
                acc[1][n] = __builtin_amdgcn_mfma_f32_16x16x32_bf16(a1h[ks], bh, acc[1][n], 0, 0, 0);
                acc[1][n] = __builtin_amdgcn_mfma_f32_16x16x32_bf16(a1h[ks], bl, acc[1][n], 0, 0, 0);
                acc[1][n] = __builtin_amdgcn_mfma_f32_16x16x32_bf16(a1l[ks], bh, acc[1][n], 0, 0, 0);
            }
        }

        float bcol[8];
#pragma unroll
        for (int n = 0; n < 8; n++)
            bcol[n] = (t < 4) ? bl1[t * 128 + n * 16 + lr] : br1[(t - 4) * 128 + n * 16 + lr];

#pragma unroll
        for (int mf = 0; mf < 2; mf++) {
#pragma unroll
            for (int r = 0; r < 4; r++) {
                int row = m0 + mf * 16 + kg * 4 + r;
                if (row >= M) continue;
#pragma unroll
                for (int n = 0; n < 8; n++)
                    out[(size_t)row * 1024 + t * 128 + n * 16 + lr] = f2bf(acc[mf][n][r] + bcol[n]);
            }
        }
    }
}

// ---------------- xl2/xr2: K=512 in-register accumulation, LDS-staged B ----------------

__global__ __launch_bounds__(256) void gemm_xlr2(
    const ushort* __restrict__ A,                                   // h1 bf16 [N][512]
    const ushort* __restrict__ wfh, const ushort* __restrict__ wfl, // full table (slots 9..16 used)
    const float* __restrict__ bl2, const float* __restrict__ br2,
    ushort* __restrict__ xl2, ushort* __restrict__ xr2, int M)
{
    __shared__ __align__(16) ushort Bh[16384];
    __shared__ __align__(16) ushort Bl[16384];

    int tid = threadIdx.x;
    int w = tid >> 6, l = tid & 63;
    int m0 = blockIdx.x * 64 + w * 16;
    int lr = l & 15, kg = l >> 4;

    int row0 = m0 + lr;
    bool ok0 = row0 < M;
    const bf16x8 zz = {0, 0, 0, 0, 0, 0, 0, 0};

    f32x4 acc[2][8];
#pragma unroll
    for (int i = 0; i < 2; i++)
#pragma unroll
        for (int j = 0; j < 8; j++) acc[i][j] = (f32x4){0.f, 0.f, 0.f, 0.f};

    for (int kc = 0; kc < 4; kc++) {
        bf16x8 ah[4];
#pragma unroll
        for (int ks = 0; ks < 4; ks++)
            ah[ks] = ok0 ? *(const bf16x8*)(A + (size_t)row0 * 512 + kc * 128 + ks * 32 + kg * 8) : zz;

        for (int t = 0; t < 2; t++) {
            int slot = 9 + t * 4 + kc;
            __syncthreads();
            {
                const float4* gh = (const float4*)(wfh + (size_t)slot * 16384);
                const float4* gl = (const float4*)(wfl + (size_t)slot * 16384);
                float4* sh = (float4*)Bh;
                float4* sl = (float4*)Bl;
#pragma unroll
                for (int i = 0; i < 8; i++) {
                    sh[i * 256 + tid] = gh[i * 256 + tid];
                    sl[i * 256 + tid] = gl[i * 256 + tid];
                }
            }
            __syncthreads();
#pragma unroll
            for (int ks = 0; ks < 4; ks++) {
#pragma unroll
                for (int n = 0; n < 8; n++) {
                    int bo = ((ks * 8 + n) * 64 + l) * 8;
                    bf16x8 bh = *(const bf16x8*)(Bh + bo);
                    bf16x8 bl = *(const bf16x8*)(Bl + bo);
                    acc[t][n] = __builtin_amdgcn_mfma_f32_16x16x32_bf16(ah[ks], bh, acc[t][n], 0, 0, 0);
                    acc[t][n] = __builtin_amdgcn_mfma_f32_16x16x32_bf16(ah[ks], bl, acc[t][n], 0, 0, 0);
                }
            }
        }
    }

#pragma unroll
    for (int r = 0; r < 4; r++) {
        int row = m0 + kg * 4 + r;
        if (row >= M) continue;
#pragma unroll
        for (int n = 0; n < 8; n++) {
            int col = n * 16 + lr;
            xl2[(size_t)row * 128 + col] = f2bf(acc[0][n][r] + bl2[col]);
            xr2[(size_t)row * 128 + col] = f2bf(acc[1][n][r] + br2[col]);
        }
    }
}

// ---------------- GAT1 edge kernel: 4 heads fused, block = node, wave = head ----------------

__global__ __launch_bounds__(256) void gat_edge4(
    const ushort* __restrict__ xlr,   // [N][8][128] bf16 (0-3 xl, 4-7 xr)
    const float* __restrict__ att,    // [4][128]
    const float* __restrict__ bias,   // [512]
    const int* __restrict__ rowptr, const int* __restrict__ colA,
    ushort* __restrict__ h1,          // [N][512] bf16 out (relu'd)
    int N)
{
    int n = blockIdx.x;
    int h = threadIdx.x >> 6, l = threadIdx.x & 63;

    unsigned xrv = *(const unsigned*)(xlr + (size_t)n * 1024 + (4 + h) * 128 + 2 * l);
    float xr0 = __uint_as_float(xrv << 16);
    float xr1 = __uint_as_float(xrv & 0xffff0000u);
    float at0 = att[h * 128 + 2 * l], at1 = att[h * 128 + 2 * l + 1];

    int k0 = rowptr[n], k1 = rowptr[n + 1];
    float m = -INFINITY, s = 0.f, o0 = 0.f, o1 = 0.f;

    int srcn = colA[k0];
    unsigned v = *(const unsigned*)(xlr + (size_t)srcn * 1024 + h * 128 + 2 * l);
    for (int k = k0; k < k1; k++) {
        unsigned nx = 0;
        if (k + 1 < k1) {
            int ns = colA[k + 1];
            nx = *(const unsigned*)(xlr + (size_t)ns * 1024 + h * 128 + 2 * l);
        }
        float v0 = __uint_as_float(v << 16);
        float v1 = __uint_as_float(v & 0xffff0000u);
        float t0 = v0 + xr0; t0 = (t0 > 0.f) ? t0 : 0.2f * t0;
        float t1 = v1 + xr1; t1 = (t1 > 0.f) ? t1 : 0.2f * t1;
        float c = t0 * at0 + t1 * at1;
#pragma unroll
        for (int off = 32; off > 0; off >>= 1)
            c += __shfl_xor(c, off);
        if (c > m) {
            float sc = __expf(m - c);
            s *= sc; o0 *= sc; o1 *= sc;
            m = c;
        }
        float p = __expf(c - m);
        s += p; o0 += p * v0; o1 += p * v1;
        v = nx;
    }

    float inv = 1.f / (s + 1e-16f);
    float r0 = fmaxf(o0 * inv + bias[h * 128 + 2 * l], 0.f);
    float r1 = fmaxf(o1 * inv + bias[h * 128 + 2 * l + 1], 0.f);
    unsigned pack = (unsigned)f2bf(r0) | ((unsigned)f2bf(r1) << 16);
    *(unsigned*)(h1 + (size_t)n * 512 + h * 128 + 2 * l) = pack;
}

// ---------------- GAT2 edge kernel: 1 head, wave = node ----------------

__global__ __launch_bounds__(64) void gat_edge1(
    const ushort* __restrict__ xl, const ushort* __restrict__ xr,  // [N][128] bf16
    const float* __restrict__ att, const float* __restrict__ bias,
    const int* __restrict__ rowptr, const int* __restrict__ colA,
    float* __restrict__ out, int N)
{
    int n = blockIdx.x;
    int l = threadIdx.x;

    unsigned xrv = *(const unsigned*)(xr + (size_t)n * 128 + 2 * l);
    float xr0 = __uint_as_float(xrv << 16);
    float xr1 = __uint_as_float(xrv & 0xffff0000u);
    float at0 = att[2 * l], at1 = att[2 * l + 1];

    int k0 = rowptr[n], k1 = rowptr[n + 1];
    float m = -INFINITY, s = 0.f, o0 = 0.f, o1 = 0.f;

    int srcn = colA[k0];
    unsigned v = *(const unsigned*)(xl + (size_t)srcn * 128 + 2 * l);
    for (int k = k0; k < k1; k++) {
        unsigned nx = 0;
        if (k + 1 < k1) {
            int ns = colA[k + 1];
            nx = *(const unsigned*)(xl + (size_t)ns * 128 + 2 * l);
        }
        float v0 = __uint_as_float(v << 16);
        float v1 = __uint_as_float(v & 0xffff0000u);
        float t0 = v0 + xr0; t0 = (t0 > 0.f) ? t0 : 0.2f * t0;
        float t1 = v1 + xr1; t1 = (t1 > 0.f) ? t1 : 0.2f * t1;
        float c = t0 * at0 + t1 * at1;
#pragma unroll
        for (int off = 32; off > 0; off >>= 1)
            c += __shfl_xor(c, off);
        if (c > m) {
            float sc = __expf(m - c);
            s *= sc; o0 *= sc; o1 *= sc;
            m = c;
        }
        float p = __expf(c - m);
        s += p; o0 += p * v0; o1 += p * v1;
        v = nx;
    }

    float inv = 1.f / (s + 1e-16f);
    float2 r;
    r.x = o0 * inv + bias[2 * l];
    r.y = o1 * inv + bias[2 * l + 1];
    *(float2*)(out + (size_t)n * 128 + 2 * l) = r;
}

// ---------------- launch ----------------

extern "C" void kernel_launch(void* const* d_in, const int* in_sizes, int n_in,
                              void* d_out, int out_size, void* d_ws, size_t ws_size,
                              hipStream_t stream) {
    const float* x    = (const float*)d_in[0];
    const int* ei     = (const int*)d_in[1];
    const float* W1   = (const float*)d_in[2];
    const float* b1   = (const float*)d_in[3];
    const float* W2   = (const float*)d_in[4];
    const float* b2   = (const float*)d_in[5];
    const float* Wl1  = (const float*)d_in[6];
    const float* bl1  = (const float*)d_in[7];
    const float* Wr1  = (const float*)d_in[8];
    const float* br1  = (const float*)d_in[9];
    const float* att1 = (const float*)d_in[10];
    const float* bias1= (const float*)d_in[11];
    const float* Wl2  = (const float*)d_in[12];
    const float* bl2  = (const float*)d_in[13];
    const float* Wr2  = (const float*)d_in[14];
    const float* br2  = (const float*)d_in[15];
    const float* att2 = (const float*)d_in[16];
    const float* bias2= (const float*)d_in[17];

    int E = in_sizes[1] / 2;
    int N = in_sizes[0] / 5;
    const int* srcE = ei;
    const int* dstE = ei + E;

    float* dout = (float*)d_out;

    // workspace (~184 MB)
    ushort* xlr1 = (ushort*)d_ws;                  // N*1024
    ushort* h1   = xlr1 + (size_t)N * 1024;        // N*512
    ushort* h0h  = h1 + (size_t)N * 512;           // N*128
    ushort* h0l  = h0h + (size_t)N * 128;          // N*128
    ushort* wfh  = h0l + (size_t)N * 128;          // 17*16384
    ushort* wfl  = wfh + 17 * 16384;
    int* rowptr = (int*)(wfl + 17 * 16384);
    int* cursor = rowptr + (N + 1);
    int* counts = cursor + N;
    int* colA   = counts + N;                      // E+N
    int* bsum   = colA + (E + N);
    int* boff   = bsum + 256;

    // aliases
    ushort* cCh = h1;                 // MLP hidden (dead before h1 written)
    ushort* cCl = h1 + (size_t)N * 128;
    ushort* xl2 = h0h;                // h0 dead after gemm_xlr1
    ushort* xr2 = h0l;

    int NB = (N + 255) / 256;

    // ---- CSR ----
    k_init <<<(N + 255) / 256, 256, 0, stream>>>(counts, N);
    k_count<<<(E + 255) / 256, 256, 0, stream>>>(srcE, dstE, E, counts);
    k_blocksum <<<NB, 256, 0, stream>>>(counts, N, bsum);
    k_scanblocks<<<1, 256, 0, stream>>>(bsum, NB, boff, rowptr, N);
    k_scatter  <<<NB, 256, 0, stream>>>(counts, N, boff, rowptr, cursor);
    k_fill <<<(E + N + 255) / 256, 256, 0, stream>>>(srcE, dstE, E, N, cursor, colA);

    // ---- repack ----
    {
        dim3 g(8, 17);
        k_repack<<<g, 256, 0, stream>>>(W2, Wl1, Wr1, Wl2, Wr2, wfh, wfl);
    }

    int mb128 = (N + 127) / 128;
    int mb64  = (N + 63) / 64;

    // ---- MLP ----
    k_mlp1<<<(N + 1) / 2, 256, 0, stream>>>(x, W1, b1, cCh, cCl, N);
    gemm_mfma<<<mb128, 256, 0, stream>>>(cCh, cCl, wfh, wfl, b2, h0h, h0l, N);

    // ---- GAT1: projections (8 slots), fused 4-head edge pass ----
    gemm_xlr1<<<mb128, 256, 0, stream>>>(h0h, h0l, wfh + 16384, wfl + 16384,
                                         bl1, br1, xlr1, N);
    gat_edge4<<<N, 256, 0, stream>>>(xlr1, att1, bias1, rowptr, colA, h1, N);

    // ---- GAT2: K=512 projections, edge pass ----
    gemm_xlr2<<<mb64, 256, 0, stream>>>(h1, wfh, wfl, bl2, br2, xl2, xr2, N);
    gat_edge1<<<N, 64, 0, stream>>>(xl2, xr2, att2, bias2, rowptr, colA, dout, N);
}

// Round 5
// 386.050 us; speedup vs baseline: 2.9590x; 1.1812x over previous
//
#include <hip/hip_runtime.h>
#include <math.h>

typedef __attribute__((ext_vector_type(8))) short bf16x8;
typedef __attribute__((ext_vector_type(4))) float f32x4;
typedef unsigned short ushort;

static __device__ __forceinline__ ushort f2bf(float f) {
    unsigned u = __float_as_uint(f);
    u = u + 0x7fff + ((u >> 16) & 1);
    return (ushort)(u >> 16);
}
static __device__ __forceinline__ float bf2f(ushort h) {
    return __uint_as_float(((unsigned)h) << 16);
}

// ---------------- CSR build ----------------

__global__ void k_init(int* __restrict__ counts, int N) {
    int i = blockIdx.x * blockDim.x + threadIdx.x;
    if (i < N) counts[i] = 1;  // self-loop
}

__global__ void k_count(const int* __restrict__ src, const int* __restrict__ dst,
                        int E, int* __restrict__ counts) {
    int e = blockIdx.x * blockDim.x + threadIdx.x;
    if (e < E) {
        int s = src[e], d = dst[e];
        if (s != d) atomicAdd(&counts[d], 1);
    }
}

__global__ __launch_bounds__(256) void k_blocksum(const int* __restrict__ counts, int N,
                                                  int* __restrict__ bsum) {
    __shared__ int s[256];
    int t = threadIdx.x, i = blockIdx.x * 256 + t;
    s[t] = (i < N) ? counts[i] : 0;
    __syncthreads();
    for (int off = 128; off > 0; off >>= 1) {
        if (t < off) s[t] += s[t + off];
        __syncthreads();
    }
    if (t == 0) bsum[blockIdx.x] = s[0];
}

__global__ __launch_bounds__(256) void k_scanblocks(const int* __restrict__ bsum, int NB,
                                                    int* __restrict__ boff,
                                                    int* __restrict__ rowptr, int N) {
    __shared__ int s[256];
    int t = threadIdx.x;
    int v = (t < NB) ? bsum[t] : 0;
    s[t] = v;
    __syncthreads();
    for (int off = 1; off < 256; off <<= 1) {
        int u = (t >= off) ? s[t - off] : 0;
        __syncthreads();
        s[t] += u;
        __syncthreads();
    }
    if (t < NB) boff[t] = s[t] - v;
    if (t == NB - 1) rowptr[N] = s[t];
}

__global__ __launch_bounds__(256) void k_scatter(const int* __restrict__ counts, int N,
                                                 const int* __restrict__ boff,
                                                 int* __restrict__ rowptr,
                                                 int* __restrict__ cursor) {
    __shared__ int s[256];
    int t = threadIdx.x, i = blockIdx.x * 256 + t;
    int c = (i < N) ? counts[i] : 0;
    s[t] = c;
    __syncthreads();
    for (int off = 1; off < 256; off <<= 1) {
        int u = (t >= off) ? s[t - off] : 0;
        __syncthreads();
        s[t] += u;
        __syncthreads();
    }
    if (i < N) {
        int excl = boff[blockIdx.x] + s[t] - c;
        rowptr[i] = excl;
        cursor[i] = excl;
    }
}

__global__ void k_fill(const int* __restrict__ src, const int* __restrict__ dst,
                       int E, int N, int* __restrict__ cursor, int* __restrict__ colA) {
    int i = blockIdx.x * blockDim.x + threadIdx.x;
    if (i < E) {
        int s = src[i], d = dst[i];
        if (s != d) { int p = atomicAdd(&cursor[d], 1); colA[p] = s; }
    } else if (i < E + N) {
        int n = i - E;
        int p = atomicAdd(&cursor[n], 1); colA[p] = n;
    }
}

// ---------------- weight repack into MFMA-fragment-major, split bf16 ----------------
// slot j: 0 = W2; 1-4 = Wl1 head cols; 5-8 = Wr1 head cols; 9-12 = Wl2 k-chunks; 13-16 = Wr2.
// Wf[ks][n][l][j] = W[rowoff + ks*32 + (l>>4)*8 + j][col0 + n*16 + (l&15)], slot stride 16384.

__global__ __launch_bounds__(256) void k_repack(
    const float* __restrict__ W2, const float* __restrict__ Wl1,
    const float* __restrict__ Wr1, const float* __restrict__ Wl2,
    const float* __restrict__ Wr2,
    ushort* __restrict__ wfh, ushort* __restrict__ wfl)
{
    int job = blockIdx.y;
    int t = blockIdx.x * 256 + threadIdx.x;  // 0..2047
    int ks = t >> 9, n = (t >> 6) & 7, l = t & 63;

    const float* W; int ldw, rowoff, col0;
    if (job == 0)      { W = W2;  ldw = 128; rowoff = 0;              col0 = 0; }
    else if (job < 5)  { W = Wl1; ldw = 512; rowoff = 0;              col0 = (job - 1) * 128; }
    else if (job < 9)  { W = Wr1; ldw = 512; rowoff = 0;              col0 = (job - 5) * 128; }
    else if (job < 13) { W = Wl2; ldw = 128; rowoff = (job - 9) * 128;  col0 = 0; }
    else               { W = Wr2; ldw = 128; rowoff = (job - 13) * 128; col0 = 0; }

    int krow = rowoff + ks * 32 + (l >> 4) * 8;
    int col = col0 + n * 16 + (l & 15);
    size_t dbase = (size_t)job * 16384 + (((size_t)(ks * 8 + n)) * 64 + l) * 8;
#pragma unroll
    for (int j = 0; j < 8; j++) {
        float v = W[(size_t)(krow + j) * ldw + col];
        ushort h = f2bf(v);
        ushort lo = f2bf(v - bf2f(h));
        wfh[dbase + j] = h;
        wfl[dbase + j] = lo;
    }
}

// ---------------- MLP layer 1 ----------------

__global__ __launch_bounds__(256) void k_mlp1(
    const float* __restrict__ x, const float* __restrict__ W1, const float* __restrict__ b1,
    ushort* __restrict__ outh, ushort* __restrict__ outl, int N)
{
    int n = blockIdx.x * 2 + (threadIdx.x >> 7);
    int j = threadIdx.x & 127;
    if (n >= N) return;
    float s = b1[j];
#pragma unroll
    for (int k = 0; k < 5; k++) s = fmaf(x[(size_t)n * 5 + k], W1[k * 128 + j], s);
    s = fmaxf(s, 0.f);
    ushort h = f2bf(s);
    outh[(size_t)n * 128 + j] = h;
    outl[(size_t)n * 128 + j] = f2bf(s - bf2f(h));
}

// ---------------- h0 GEMM (bf16x3, B from global): split in, split out ----------------

__global__ __launch_bounds__(256) void gemm_mfma(
    const ushort* __restrict__ Ah, const ushort* __restrict__ Al,
    const ushort* __restrict__ wfh, const ushort* __restrict__ wfl,
    const float* __restrict__ bias,
    ushort* __restrict__ Ch, ushort* __restrict__ Cl,
    int M)
{
    int tid = threadIdx.x;
    int w = tid >> 6, l = tid & 63;
    int m0 = blockIdx.x * 128 + w * 32;
    int lr = l & 15, kg = l >> 4;

    f32x4 acc[2][8];
#pragma unroll
    for (int i = 0; i < 2; i++)
#pragma unroll
        for (int j = 0; j < 8; j++) acc[i][j] = (f32x4){0.f, 0.f, 0.f, 0.f};

    int row0 = m0 + lr, row1 = m0 + 16 + lr;
    bool ok0 = row0 < M, ok1 = row1 < M;
    const bf16x8 zz = {0, 0, 0, 0, 0, 0, 0, 0};

#pragma unroll
    for (int ks = 0; ks < 4; ks++) {
        int koff = ks * 32 + kg * 8;
        bf16x8 a0h = ok0 ? *(const bf16x8*)(Ah + (size_t)row0 * 128 + koff) : zz;
        bf16x8 a0l = ok0 ? *(const bf16x8*)(Al + (size_t)row0 * 128 + koff) : zz;
        bf16x8 a1h = ok1 ? *(const bf16x8*)(Ah + (size_t)row1 * 128 + koff) : zz;
        bf16x8 a1l = ok1 ? *(const bf16x8*)(Al + (size_t)row1 * 128 + koff) : zz;
#pragma unroll
        for (int n = 0; n < 8; n++) {
            size_t bo = (((size_t)(ks * 8 + n)) * 64 + l) * 8;
            bf16x8 bh = *(const bf16x8*)(wfh + bo);
            bf16x8 bl = *(const bf16x8*)(wfl + bo);
            acc[0][n] = __builtin_amdgcn_mfma_f32_16x16x32_bf16(a0h, bh, acc[0][n], 0, 0, 0);
            acc[0][n] = __builtin_amdgcn_mfma_f32_16x16x32_bf16(a0h, bl, acc[0][n], 0, 0, 0);
            acc[0][n] = __builtin_amdgcn_mfma_f32_16x16x32_bf16(a0l, bh, acc[0][n], 0, 0, 0);
            acc[1][n] = __builtin_amdgcn_mfma_f32_16x16x32_bf16(a1h, bh, acc[1][n], 0, 0, 0);
            acc[1][n] = __builtin_amdgcn_mfma_f32_16x16x32_bf16(a1h, bl, acc[1][n], 0, 0, 0);
            acc[1][n] = __builtin_amdgcn_mfma_f32_16x16x32_bf16(a1l, bh, acc[1][n], 0, 0, 0);
        }
    }

#pragma unroll
    for (int mf = 0; mf < 2; mf++) {
#pragma unroll
        for (int r = 0; r < 4; r++) {
            int row = m0 + mf * 16 + kg * 4 + r;
            if (row >= M) continue;
#pragma unroll
            for (int n = 0; n < 8; n++) {
                size_t idx = (size_t)row * 128 + n * 16 + lr;
                float v = acc[mf][n][r] + bias[n * 16 + lr];
                ushort h = f2bf(v);
                Ch[idx] = h;
                Cl[idx] = f2bf(v - bf2f(h));
            }
        }
    }
}

// ---------------- xl/xr projection for all 8 head-slots, LDS-staged B ----------------
// out: [N][8][128] bf16.  slots base = wfh + 1*16384 (Wl1 heads 0-3, Wr1 heads 0-3).

__global__ __launch_bounds__(256) void gemm_xlr1(
    const ushort* __restrict__ Ah, const ushort* __restrict__ Al,  // h0 split [N][128]
    const ushort* __restrict__ wh, const ushort* __restrict__ wl,  // slot-1 base
    const float* __restrict__ bl1, const float* __restrict__ br1,  // [512] each
    ushort* __restrict__ out, int M)
{
    __shared__ __align__(16) ushort Bh[16384];
    __shared__ __align__(16) ushort Bl[16384];

    int tid = threadIdx.x;
    int w = tid >> 6, l = tid & 63;
    int m0 = blockIdx.x * 128 + w * 32;
    int lr = l & 15, kg = l >> 4;

    int row0 = m0 + lr, row1 = m0 + 16 + lr;
    bool ok0 = row0 < M, ok1 = row1 < M;
    const bf16x8 zz = {0, 0, 0, 0, 0, 0, 0, 0};

    bf16x8 a0h[4], a0l[4], a1h[4], a1l[4];
#pragma unroll
    for (int ks = 0; ks < 4; ks++) {
        int koff = ks * 32 + kg * 8;
        a0h[ks] = ok0 ? *(const bf16x8*)(Ah + (size_t)row0 * 128 + koff) : zz;
        a0l[ks] = ok0 ? *(const bf16x8*)(Al + (size_t)row0 * 128 + koff) : zz;
        a1h[ks] = ok1 ? *(const bf16x8*)(Ah + (size_t)row1 * 128 + koff) : zz;
        a1l[ks] = ok1 ? *(const bf16x8*)(Al + (size_t)row1 * 128 + koff) : zz;
    }

    for (int t = 0; t < 8; t++) {
        __syncthreads();
        {
            const float4* gh = (const float4*)(wh + (size_t)t * 16384);
            const float4* gl = (const float4*)(wl + (size_t)t * 16384);
            float4* sh = (float4*)Bh;
            float4* sl = (float4*)Bl;
#pragma unroll
            for (int i = 0; i < 8; i++) {
                sh[i * 256 + tid] = gh[i * 256 + tid];
                sl[i * 256 + tid] = gl[i * 256 + tid];
            }
        }
        __syncthreads();

        f32x4 acc[2][8];
#pragma unroll
        for (int i = 0; i < 2; i++)
#pragma unroll
            for (int j = 0; j < 8; j++) acc[i][j] = (f32x4){0.f, 0.f, 0.f, 0.f};

#pragma unroll
        for (int ks = 0; ks < 4; ks++) {
#pragma unroll
            for (int n = 0; n < 8; n++) {
                int bo = ((ks * 8 + n) * 64 + l) * 8;
                bf16x8 bh = *(const bf16x8*)(Bh + bo);
                bf16x8 bl = *(const bf16x8*)(Bl + bo);
                acc[0][n] = __builtin_amdgcn_mfma_f32_16x16x32_bf16(a0h[ks], bh, acc[0][n], 0, 0, 0);
                acc[0][n] = __builtin_amdgcn_mfma_f32_16x16x32_bf16(a0h[ks], bl, acc[0][n], 0, 0, 0);
                acc[0][n] = __builtin_amdgcn_mfma_f32_16x16x32_bf16(a0l[ks], bh, acc[0][n], 0, 0, 0);
                acc[1][n] = __builtin_amdgcn_mfma_f32_16x16x32_bf16(a1h[ks], bh, acc[1][n], 0, 0, 0);
                acc[1][n] = __builtin_amdgcn_mfma_f32_16x16x32_bf16(a1h[ks], bl, acc[1][n], 0, 0, 0);
                acc[1][n] = __builtin_amdgcn_mfma_f32_16x16x32_bf16(a1l[ks], bh, acc[1][n], 0, 0, 0);
            }
        }

        float bcol[8];
#pragma unroll
        for (int n = 0; n < 8; n++)
            bcol[n] = (t < 4) ? bl1[t * 128 + n * 16 + lr] : br1[(t - 4) * 128 + n * 16 + lr];

#pragma unroll
        for (int mf = 0; mf < 2; mf++) {
#pragma unroll
            for (int r = 0; r < 4; r++) {
                int row = m0 + mf * 16 + kg * 4 + r;
                if (row >= M) continue;
#pragma unroll
                for (int n = 0; n < 8; n++)
                    out[(size_t)row * 1024 + t * 128 + n * 16 + lr] = f2bf(acc[mf][n][r] + bcol[n]);
            }
        }
    }
}

// ---------------- xl2/xr2: K=512 in-register accumulation, LDS-staged B ----------------

__global__ __launch_bounds__(256) void gemm_xlr2(
    const ushort* __restrict__ A,                                   // h1 bf16 [N][512]
    const ushort* __restrict__ wfh, const ushort* __restrict__ wfl, // full table (slots 9..16 used)
    const float* __restrict__ bl2, const float* __restrict__ br2,
    ushort* __restrict__ xl2, ushort* __restrict__ xr2, int M)
{
    __shared__ __align__(16) ushort Bh[16384];
    __shared__ __align__(16) ushort Bl[16384];

    int tid = threadIdx.x;
    int w = tid >> 6, l = tid & 63;
    int m0 = blockIdx.x * 64 + w * 16;
    int lr = l & 15, kg = l >> 4;

    int row0 = m0 + lr;
    bool ok0 = row0 < M;
    const bf16x8 zz = {0, 0, 0, 0, 0, 0, 0, 0};

    f32x4 acc[2][8];
#pragma unroll
    for (int i = 0; i < 2; i++)
#pragma unroll
        for (int j = 0; j < 8; j++) acc[i][j] = (f32x4){0.f, 0.f, 0.f, 0.f};

    for (int kc = 0; kc < 4; kc++) {
        bf16x8 ah[4];
#pragma unroll
        for (int ks = 0; ks < 4; ks++)
            ah[ks] = ok0 ? *(const bf16x8*)(A + (size_t)row0 * 512 + kc * 128 + ks * 32 + kg * 8) : zz;

        for (int t = 0; t < 2; t++) {
            int slot = 9 + t * 4 + kc;
            __syncthreads();
            {
                const float4* gh = (const float4*)(wfh + (size_t)slot * 16384);
                const float4* gl = (const float4*)(wfl + (size_t)slot * 16384);
                float4* sh = (float4*)Bh;
                float4* sl = (float4*)Bl;
#pragma unroll
                for (int i = 0; i < 8; i++) {
                    sh[i * 256 + tid] = gh[i * 256 + tid];
                    sl[i * 256 + tid] = gl[i * 256 + tid];
                }
            }
            __syncthreads();
#pragma unroll
            for (int ks = 0; ks < 4; ks++) {
#pragma unroll
                for (int n = 0; n < 8; n++) {
                    int bo = ((ks * 8 + n) * 64 + l) * 8;
                    bf16x8 bh = *(const bf16x8*)(Bh + bo);
                    bf16x8 bl = *(const bf16x8*)(Bl + bo);
                    acc[t][n] = __builtin_amdgcn_mfma_f32_16x16x32_bf16(ah[ks], bh, acc[t][n], 0, 0, 0);
                    acc[t][n] = __builtin_amdgcn_mfma_f32_16x16x32_bf16(ah[ks], bl, acc[t][n], 0, 0, 0);
                }
            }
        }
    }

#pragma unroll
    for (int r = 0; r < 4; r++) {
        int row = m0 + kg * 4 + r;
        if (row >= M) continue;
#pragma unroll
        for (int n = 0; n < 8; n++) {
            int col = n * 16 + lr;
            xl2[(size_t)row * 128 + col] = f2bf(acc[0][n][r] + bl2[col]);
            xr2[(size_t)row * 128 + col] = f2bf(acc[1][n][r] + br2[col]);
        }
    }
}

// ---------------- GAT1 edge kernel: 4 heads fused, 16-lane groups, 4 edges in flight ----------------
// block = node, wave = head; group g (16 lanes) handles edges k0+g, k0+g+4, ...
// lane q owns dims q*8..q*8+7 (one bf16x8 = 16B load; group reads a contiguous 256B slice).

__global__ __launch_bounds__(256) void gat_edge4(
    const ushort* __restrict__ xlr,   // [N][8][128] bf16 (0-3 xl, 4-7 xr)
    const float* __restrict__ att,    // [4][128]
    const float* __restrict__ bias,   // [512]
    const int* __restrict__ rowptr, const int* __restrict__ colA,
    ushort* __restrict__ h1,          // [N][512] bf16 out (relu'd)
    int N)
{
    int n = blockIdx.x;
    int h = threadIdx.x >> 6, l = threadIdx.x & 63;
    int g = l >> 4, q = l & 15;
    const bf16x8 zz = {0, 0, 0, 0, 0, 0, 0, 0};

    bf16x8 xrv = *(const bf16x8*)(xlr + (size_t)n * 1024 + (4 + h) * 128 + q * 8);
    float xr[8], at[8];
#pragma unroll
    for (int j = 0; j < 8; j++) {
        xr[j] = bf2f((ushort)xrv[j]);
        at[j] = att[h * 128 + q * 8 + j];
    }

    int k0 = rowptr[n], k1 = rowptr[n + 1];
    float m = -INFINITY, s = 0.f;
    float o[8];
#pragma unroll
    for (int j = 0; j < 8; j++) o[j] = 0.f;

    int k = k0 + g;
    bf16x8 vv = zz;
    if (k < k1) {
        int srcn = colA[k];
        vv = *(const bf16x8*)(xlr + (size_t)srcn * 1024 + h * 128 + q * 8);
    }
    for (; k < k1; k += 4) {
        bf16x8 nv = zz;
        if (k + 4 < k1) {
            int ns = colA[k + 4];
            nv = *(const bf16x8*)(xlr + (size_t)ns * 1024 + h * 128 + q * 8);
        }
        float v[8], c = 0.f;
#pragma unroll
        for (int j = 0; j < 8; j++) {
            v[j] = bf2f((ushort)vv[j]);
            float t = v[j] + xr[j];
            t = (t > 0.f) ? t : 0.2f * t;
            c = fmaf(t, at[j], c);
        }
        c += __shfl_xor(c, 1);
        c += __shfl_xor(c, 2);
        c += __shfl_xor(c, 4);
        c += __shfl_xor(c, 8);
        if (c > m) {
            float sc = __expf(m - c);
            s *= sc;
#pragma unroll
            for (int j = 0; j < 8; j++) o[j] *= sc;
            m = c;
        }
        float p = __expf(c - m);
        s += p;
#pragma unroll
        for (int j = 0; j < 8; j++) o[j] = fmaf(p, v[j], o[j]);
        vv = nv;
    }

    // merge 4 group states (flash combine), xor 16 then 32
#pragma unroll
    for (int off = 16; off <= 32; off <<= 1) {
        float m2 = __shfl_xor(m, off);
        float s2 = __shfl_xor(s, off);
        float o2[8];
#pragma unroll
        for (int j = 0; j < 8; j++) o2[j] = __shfl_xor(o[j], off);
        float nm = fmaxf(m, m2);
        float fa = (m > -INFINITY) ? __expf(m - nm) : 0.f;
        float fb = (m2 > -INFINITY) ? __expf(m2 - nm) : 0.f;
        s = s * fa + s2 * fb;
#pragma unroll
        for (int j = 0; j < 8; j++) o[j] = o[j] * fa + o2[j] * fb;
        m = nm;
    }

    if (g == 0) {
        float inv = 1.f / (s + 1e-16f);
        bf16x8 pk;
#pragma unroll
        for (int j = 0; j < 8; j++) {
            float r = fmaxf(o[j] * inv + bias[h * 128 + q * 8 + j], 0.f);
            pk[j] = (short)f2bf(r);
        }
        *(bf16x8*)(h1 + (size_t)n * 512 + h * 128 + q * 8) = pk;
    }
}

// ---------------- GAT2 edge kernel: 1 head, wave = node, 16-lane groups ----------------

__global__ __launch_bounds__(256) void gat_edge1(
    const ushort* __restrict__ xl, const ushort* __restrict__ xr,  // [N][128] bf16
    const float* __restrict__ att, const float* __restrict__ bias,
    const int* __restrict__ rowptr, const int* __restrict__ colA,
    float* __restrict__ out, int N)
{
    int n = blockIdx.x * 4 + (threadIdx.x >> 6);
    if (n >= N) return;
    int l = threadIdx.x & 63;
    int g = l >> 4, q = l & 15;
    const bf16x8 zz = {0, 0, 0, 0, 0, 0, 0, 0};

    bf16x8 xrv = *(const bf16x8*)(xr + (size_t)n * 128 + q * 8);
    float xrr[8], at[8];
#pragma unroll
    for (int j = 0; j < 8; j++) {
        xrr[j] = bf2f((ushort)xrv[j]);
        at[j] = att[q * 8 + j];
    }

    int k0 = rowptr[n], k1 = rowptr[n + 1];
    float m = -INFINITY, s = 0.f;
    float o[8];
#pragma unroll
    for (int j = 0; j < 8; j++) o[j] = 0.f;

    int k = k0 + g;
    bf16x8 vv = zz;
    if (k < k1) {
        int srcn = colA[k];
        vv = *(const bf16x8*)(xl + (size_t)srcn * 128 + q * 8);
    }
    for (; k < k1; k += 4) {
        bf16x8 nv = zz;
        if (k + 4 < k1) {
            int ns = colA[k + 4];
            nv = *(const bf16x8*)(xl + (size_t)ns * 128 + q * 8);
        }
        float v[8], c = 0.f;
#pragma unroll
        for (int j = 0; j < 8; j++) {
            v[j] = bf2f((ushort)vv[j]);
            float t = v[j] + xrr[j];
            t = (t > 0.f) ? t : 0.2f * t;
            c = fmaf(t, at[j], c);
        }
        c += __shfl_xor(c, 1);
        c += __shfl_xor(c, 2);
        c += __shfl_xor(c, 4);
        c += __shfl_xor(c, 8);
        if (c > m) {
            float sc = __expf(m - c);
            s *= sc;
#pragma unroll
            for (int j = 0; j < 8; j++) o[j] *= sc;
            m = c;
        }
        float p = __expf(c - m);
        s += p;
#pragma unroll
        for (int j = 0; j < 8; j++) o[j] = fmaf(p, v[j], o[j]);
        vv = nv;
    }

#pragma unroll
    for (int off = 16; off <= 32; off <<= 1) {
        float m2 = __shfl_xor(m, off);
        float s2 = __shfl_xor(s, off);
        float o2[8];
#pragma unroll
        for (int j = 0; j < 8; j++) o2[j] = __shfl_xor(o[j], off);
        float nm = fmaxf(m, m2);
        float fa = (m > -INFINITY) ? __expf(m - nm) : 0.f;
        float fb = (m2 > -INFINITY) ? __expf(m2 - nm) : 0.f;
        s = s * fa + s2 * fb;
#pragma unroll
        for (int j = 0; j < 8; j++) o[j] = o[j] * fa + o2[j] * fb;
        m = nm;
    }

    if (g == 0) {
        float inv = 1.f / (s + 1e-16f);
        float4 r0, r1;
        float* p0 = (float*)&r0; float* p1 = (float*)&r1;
#pragma unroll
        for (int j = 0; j < 4; j++) {
            p0[j] = o[j] * inv + bias[q * 8 + j];
            p1[j] = o[j + 4] * inv + bias[q * 8 + j + 4];
        }
        *(float4*)(out + (size_t)n * 128 + q * 8)     = r0;
        *(float4*)(out + (size_t)n * 128 + q * 8 + 4) = r1;
    }
}

// ---------------- launch ----------------

extern "C" void kernel_launch(void* const* d_in, const int* in_sizes, int n_in,
                              void* d_out, int out_size, void* d_ws, size_t ws_size,
                              hipStream_t stream) {
    const float* x    = (const float*)d_in[0];
    const int* ei     = (const int*)d_in[1];
    const float* W1   = (const float*)d_in[2];
    const float* b1   = (const float*)d_in[3];
    const float* W2   = (const float*)d_in[4];
    const float* b2   = (const float*)d_in[5];
    const float* Wl1  = (const float*)d_in[6];
    const float* bl1  = (const float*)d_in[7];
    const float* Wr1  = (const float*)d_in[8];
    const float* br1  = (const float*)d_in[9];
    const float* att1 = (const float*)d_in[10];
    const float* bias1= (const float*)d_in[11];
    const float* Wl2  = (const float*)d_in[12];
    const float* bl2  = (const float*)d_in[13];
    const float* Wr2  = (const float*)d_in[14];
    const float* br2  = (const float*)d_in[15];
    const float* att2 = (const float*)d_in[16];
    const float* bias2= (const float*)d_in[17];

    int E = in_sizes[1] / 2;
    int N = in_sizes[0] / 5;
    const int* srcE = ei;
    const int* dstE = ei + E;

    float* dout = (float*)d_out;

    // workspace (~184 MB)
    ushort* xlr1 = (ushort*)d_ws;                  // N*1024
    ushort* h1   = xlr1 + (size_t)N * 1024;        // N*512
    ushort* h0h  = h1 + (size_t)N * 512;           // N*128
    ushort* h0l  = h0h + (size_t)N * 128;          // N*128
    ushort* wfh  = h0l + (size_t)N * 128;          // 17*16384
    ushort* wfl  = wfh + 17 * 16384;
    int* rowptr = (int*)(wfl + 17 * 16384);
    int* cursor = rowptr + (N + 1);
    int* counts = cursor + N;
    int* colA   = counts + N;                      // E+N
    int* bsum   = colA + (E + N);
    int* boff   = bsum + 256;

    // aliases
    ushort* cCh = h1;                 // MLP hidden (dead before h1 written)
    ushort* cCl = h1 + (size_t)N * 128;
    ushort* xl2 = h0h;                // h0 dead after gemm_xlr1
    ushort* xr2 = h0l;

    int NB = (N + 255) / 256;

    // ---- CSR ----
    k_init <<<(N + 255) / 256, 256, 0, stream>>>(counts, N);
    k_count<<<(E + 255) / 256, 256, 0, stream>>>(srcE, dstE, E, counts);
    k_blocksum <<<NB, 256, 0, stream>>>(counts, N, bsum);
    k_scanblocks<<<1, 256, 0, stream>>>(bsum, NB, boff, rowptr, N);
    k_scatter  <<<NB, 256, 0, stream>>>(counts, N, boff, rowptr, cursor);
    k_fill <<<(E + N + 255) / 256, 256, 0, stream>>>(srcE, dstE, E, N, cursor, colA);

    // ---- repack ----
    {
        dim3 g(8, 17);
        k_repack<<<g, 256, 0, stream>>>(W2, Wl1, Wr1, Wl2, Wr2, wfh, wfl);
    }

    int mb128 = (N + 127) / 128;
    int mb64  = (N + 63) / 64;

    // ---- MLP ----
    k_mlp1<<<(N + 1) / 2, 256, 0, stream>>>(x, W1, b1, cCh, cCl, N);
    gemm_mfma<<<mb128, 256, 0, stream>>>(cCh, cCl, wfh, wfl, b2, h0h, h0l, N);

    // ---- GAT1: projections (8 slots), fused 4-head edge pass ----
    gemm_xlr1<<<mb128, 256, 0, stream>>>(h0h, h0l, wfh + 16384, wfl + 16384,
                                         bl1, br1, xlr1, N);
    gat_edge4<<<N, 256, 0, stream>>>(xlr1, att1, bias1, rowptr, colA, h1, N);

    // ---- GAT2: K=512 projections, edge pass ----
    gemm_xlr2<<<mb64, 256, 0, stream>>>(h1, wfh, wfl, bl2, br2, xl2, xr2, N);
    gat_edge1<<<(N + 3) / 4, 256, 0, stream>>>(xl2, xr2, att2, bias2, rowptr, colA, dout, N);
}